// Round 1
// baseline (447.832 us; speedup 1.0000x reference)
//
#include <hip/hip_runtime.h>

#define NB 8
#define NTQ 1024
#define NTM 1024
#define ND 512
#define NATTN 512
#define NH 8
#define NDH 64

typedef _Float16 half8 __attribute__((ext_vector_type(8)));
typedef float f32x4 __attribute__((ext_vector_type(4)));

// ---------------------------------------------------------------------------
// Projection: out = A @ W for A in {inputs, memory, memory}, W in {Wq,Wk,Wv}.
// z=0 -> Q fp16 [b][h][t][64]; z=1 -> K fp16 [b][h][m][64];
// z=2 -> V transposed fp16 [b][h][64][m]  (so attn PV B-frags are contiguous)
// ---------------------------------------------------------------------------
__global__ __launch_bounds__(256) void proj_kernel(
    const float* __restrict__ inputs, const float* __restrict__ memory,
    const float* __restrict__ Wq, const float* __restrict__ Wk,
    const float* __restrict__ Wv,
    _Float16* __restrict__ Qh, _Float16* __restrict__ Kh,
    _Float16* __restrict__ Vth) {
  const int z = blockIdx.z;
  const float* __restrict__ A = (z == 0) ? inputs : memory;
  const float* __restrict__ W = (z == 0) ? Wq : ((z == 1) ? Wk : Wv);
  const int row0 = blockIdx.y * 64;  // 0..8191 (b*1024 + t)
  const int col0 = blockIdx.x * 64;  // 0..511  (h*64 + d)

  __shared__ __align__(16) _Float16 As[64][72];
  __shared__ __align__(16) _Float16 Wt[64][72];  // Wt[c][k]

  const int t = threadIdx.x;
  const int w = t >> 6;
  const int L = t & 63;
  const int lrow = L & 15;
  const int quad = L >> 4;
  const int sr = t >> 2;        // 0..63
  const int sc = (t & 3) * 16;  // 0,16,32,48

  const f32x4 zf = {0.f, 0.f, 0.f, 0.f};
  f32x4 acc[4];
#pragma unroll
  for (int i = 0; i < 4; i++) acc[i] = zf;

  for (int k0 = 0; k0 < ND; k0 += 64) {
    // stage A tile fp32->fp16
    {
      const float4* src = (const float4*)(A + (size_t)(row0 + sr) * ND + k0 + sc);
      float4 f0 = src[0], f1 = src[1], f2 = src[2], f3 = src[3];
      half8 h0, h1;
      h0[0] = (_Float16)f0.x; h0[1] = (_Float16)f0.y; h0[2] = (_Float16)f0.z; h0[3] = (_Float16)f0.w;
      h0[4] = (_Float16)f1.x; h0[5] = (_Float16)f1.y; h0[6] = (_Float16)f1.z; h0[7] = (_Float16)f1.w;
      h1[0] = (_Float16)f2.x; h1[1] = (_Float16)f2.y; h1[2] = (_Float16)f2.z; h1[3] = (_Float16)f2.w;
      h1[4] = (_Float16)f3.x; h1[5] = (_Float16)f3.y; h1[6] = (_Float16)f3.z; h1[7] = (_Float16)f3.w;
      *(half8*)&As[sr][sc] = h0;
      *(half8*)&As[sr][sc + 8] = h1;
    }
    // stage W tile transposed: Wt[c][k]
    {
      const float4* src = (const float4*)(W + (size_t)(k0 + sr) * NATTN + col0 + sc);
      float4 g0 = src[0], g1 = src[1], g2 = src[2], g3 = src[3];
      float gv[16];
      *(float4*)&gv[0] = g0; *(float4*)&gv[4] = g1;
      *(float4*)&gv[8] = g2; *(float4*)&gv[12] = g3;
#pragma unroll
      for (int j = 0; j < 16; j++) Wt[sc + j][sr] = (_Float16)gv[j];
    }
    __syncthreads();
#pragma unroll
    for (int ks = 0; ks < 2; ks++) {
      half8 a = *(const half8*)&As[w * 16 + lrow][ks * 32 + quad * 8];
#pragma unroll
      for (int nt = 0; nt < 4; nt++) {
        half8 b = *(const half8*)&Wt[nt * 16 + lrow][ks * 32 + quad * 8];
        acc[nt] = __builtin_amdgcn_mfma_f32_16x16x32_f16(a, b, acc[nt], 0, 0, 0);
      }
    }
    __syncthreads();
  }

  const int b = row0 >> 10;
  const int tr0 = row0 & 1023;
  const int hh = col0 >> 6;
  if (z <= 1) {
    _Float16* dst = (z == 0 ? Qh : Kh) + (size_t)(b * NH + hh) * NTQ * NDH;
#pragma unroll
    for (int nt = 0; nt < 4; nt++) {
#pragma unroll
      for (int r = 0; r < 4; r++) {
        int trow = tr0 + w * 16 + quad * 4 + r;
        int d = nt * 16 + lrow;
        dst[(size_t)trow * NDH + d] = (_Float16)acc[nt][r];
      }
    }
  } else {
    // rebounce through LDS to write V transposed coalesced: As reused as [d][t]
#pragma unroll
    for (int nt = 0; nt < 4; nt++) {
#pragma unroll
      for (int r = 0; r < 4; r++)
        As[nt * 16 + lrow][w * 16 + quad * 4 + r] = (_Float16)acc[nt][r];
    }
    __syncthreads();
    _Float16* dst = Vth + ((size_t)(b * NH + hh) * NDH + sr) * NTM + tr0 + sc;
    *(half8*)dst = *(const half8*)&As[sr][sc];
    *(half8*)(dst + 8) = *(const half8*)&As[sr][sc + 8];
  }
}

// ---------------------------------------------------------------------------
// Attention: per block = one (b,h) x 64-query tile. Two passes over m:
// pass 1 computes softmax denominators (no max subtraction needed; logits~N(0,1),
// masked->0 exactly, fully-masked rows handled as logit=0 everywhere to match
// the reference's uniform-softmax-of-all-NEG_INF behavior).
// pass 2 recomputes S, writes normalized alignments, accumulates P@V.
// ---------------------------------------------------------------------------
__global__ __launch_bounds__(256) void attn_kernel(
    const _Float16* __restrict__ Qh, const _Float16* __restrict__ Kh,
    const _Float16* __restrict__ Vth, const int* __restrict__ mem_len,
    const int* __restrict__ qry_len, float* __restrict__ ctx_out,
    float* __restrict__ align_out) {
  const int qt = blockIdx.x;  // 0..15
  const int bh = blockIdx.y;  // 0..63
  const int bb = bh >> 3;
  const int hh = bh & 7;
  const int q0 = qt * 64;

  __shared__ __align__(16) _Float16 Qs[64][72];
  __shared__ __align__(16) _Float16 Ks[64][72];
  __shared__ __align__(16) _Float16 Vts[64][72];  // [d][m_local]
  __shared__ __align__(16) _Float16 Ps[4][16][72];  // per-wave P (A-layout src)

  const int t = threadIdx.x, w = t >> 6, L = t & 63;
  const int lrow = L & 15, quad = L >> 4;
  const int qlen = qry_len[bb], mlen = mem_len[bb];
  const _Float16* Qbase = Qh + (size_t)bh * NTQ * NDH;
  const _Float16* Kbase = Kh + (size_t)bh * NTM * NDH;
  const _Float16* Vbase = Vth + (size_t)bh * NDH * NTM;
  const int sr = t >> 2, sc = (t & 3) * 16;
  const f32x4 zf = {0.f, 0.f, 0.f, 0.f};

  {
    const half8* src = (const half8*)(Qbase + (size_t)(q0 + sr) * NDH + sc);
    *(half8*)&Qs[sr][sc] = src[0];
    *(half8*)&Qs[sr][sc + 8] = src[1];
  }
  const int qg = q0 + w * 16 + quad * 4;  // + r = global q row
  float rowsum[4] = {0.f, 0.f, 0.f, 0.f};
  __syncthreads();

  // ---- pass 1: denominators ----
  for (int mt = 0; mt < 16; mt++) {
    {
      const half8* src = (const half8*)(Kbase + (size_t)(mt * 64 + sr) * NDH + sc);
      *(half8*)&Ks[sr][sc] = src[0];
      *(half8*)&Ks[sr][sc + 8] = src[1];
    }
    __syncthreads();
    f32x4 sacc[4];
#pragma unroll
    for (int i = 0; i < 4; i++) sacc[i] = zf;
#pragma unroll
    for (int ks = 0; ks < 2; ks++) {
      half8 a = *(const half8*)&Qs[w * 16 + lrow][ks * 32 + quad * 8];
#pragma unroll
      for (int nt = 0; nt < 4; nt++) {
        half8 b = *(const half8*)&Ks[nt * 16 + lrow][ks * 32 + quad * 8];
        sacc[nt] = __builtin_amdgcn_mfma_f32_16x16x32_f16(a, b, sacc[nt], 0, 0, 0);
      }
    }
#pragma unroll
    for (int nt = 0; nt < 4; nt++) {
      int m = mt * 64 + nt * 16 + lrow;
#pragma unroll
      for (int r = 0; r < 4; r++) {
        int q = qg + r;
        float p;
        if (q >= qlen) p = 1.0f;                     // fully-masked row -> uniform
        else if (m > q || m >= mlen) p = 0.0f;       // masked element
        else p = __expf(sacc[nt][r] * 0.125f);
        rowsum[r] += p;
      }
    }
    __syncthreads();
  }
  float inv[4];
#pragma unroll
  for (int r = 0; r < 4; r++) {
    float s = rowsum[r];
    s += __shfl_xor(s, 1, 16);
    s += __shfl_xor(s, 2, 16);
    s += __shfl_xor(s, 4, 16);
    s += __shfl_xor(s, 8, 16);
    inv[r] = 1.0f / s;
  }

  // ---- pass 2: alignments + contexts ----
  f32x4 cacc[4];
#pragma unroll
  for (int i = 0; i < 4; i++) cacc[i] = zf;
  float* arow = align_out + (size_t)bh * NTQ * NTM;

  for (int mt = 0; mt < 16; mt++) {
    {
      const half8* src = (const half8*)(Kbase + (size_t)(mt * 64 + sr) * NDH + sc);
      *(half8*)&Ks[sr][sc] = src[0];
      *(half8*)&Ks[sr][sc + 8] = src[1];
      const half8* vsrc = (const half8*)(Vbase + (size_t)sr * NTM + mt * 64 + sc);
      *(half8*)&Vts[sr][sc] = vsrc[0];
      *(half8*)&Vts[sr][sc + 8] = vsrc[1];
    }
    __syncthreads();
    f32x4 sacc[4];
#pragma unroll
    for (int i = 0; i < 4; i++) sacc[i] = zf;
#pragma unroll
    for (int ks = 0; ks < 2; ks++) {
      half8 a = *(const half8*)&Qs[w * 16 + lrow][ks * 32 + quad * 8];
#pragma unroll
      for (int nt = 0; nt < 4; nt++) {
        half8 b = *(const half8*)&Ks[nt * 16 + lrow][ks * 32 + quad * 8];
        sacc[nt] = __builtin_amdgcn_mfma_f32_16x16x32_f16(a, b, sacc[nt], 0, 0, 0);
      }
    }
#pragma unroll
    for (int nt = 0; nt < 4; nt++) {
      int m = mt * 64 + nt * 16 + lrow;
#pragma unroll
      for (int r = 0; r < 4; r++) {
        int q = qg + r;
        float p;
        if (q >= qlen) p = inv[r];
        else if (m > q || m >= mlen) p = 0.0f;
        else p = __expf(sacc[nt][r] * 0.125f) * inv[r];
        arow[(size_t)q * NTM + m] = p;
        Ps[w][quad * 4 + r][nt * 16 + lrow] = (_Float16)p;
      }
    }
    // P @ V  (Ps is per-wave; in-wave DS ordering suffices, no barrier)
#pragma unroll
    for (int ks = 0; ks < 2; ks++) {
      half8 a = *(const half8*)&Ps[w][lrow][ks * 32 + quad * 8];
#pragma unroll
      for (int dt = 0; dt < 4; dt++) {
        half8 b = *(const half8*)&Vts[dt * 16 + lrow][ks * 32 + quad * 8];
        cacc[dt] = __builtin_amdgcn_mfma_f32_16x16x32_f16(a, b, cacc[dt], 0, 0, 0);
      }
    }
    __syncthreads();
  }

  float* cbase = ctx_out + (size_t)bb * NTQ * NATTN + (size_t)hh * NDH;
#pragma unroll
  for (int dt = 0; dt < 4; dt++) {
#pragma unroll
    for (int r = 0; r < 4; r++) {
      int q = qg + r;
      cbase[(size_t)q * NATTN + dt * 16 + lrow] = cacc[dt][r];
    }
  }
}

extern "C" void kernel_launch(void* const* d_in, const int* in_sizes, int n_in,
                              void* d_out, int out_size, void* d_ws,
                              size_t ws_size, hipStream_t stream) {
  const float* inputs = (const float*)d_in[0];
  const float* memory = (const float*)d_in[1];
  const float* Wq = (const float*)d_in[2];
  const float* Wk = (const float*)d_in[3];
  const float* Wv = (const float*)d_in[4];
  const int* mlen = (const int*)d_in[5];
  const int* qlen = (const int*)d_in[6];

  float* ctx = (float*)d_out;                              // (B,TQ,ATTN)
  float* align = ctx + (size_t)NB * NTQ * NATTN;           // (B,H,TQ,TM)

  _Float16* Qh = (_Float16*)d_ws;                          // 8 MB
  _Float16* Kh = Qh + (size_t)NB * NH * NTQ * NDH;         // 8 MB
  _Float16* Vth = Kh + (size_t)NB * NH * NTM * NDH;        // 8 MB

  proj_kernel<<<dim3(8, 128, 3), 256, 0, stream>>>(inputs, memory, Wq, Wk, Wv,
                                                   Qh, Kh, Vth);
  attn_kernel<<<dim3(16, 64), 256, 0, stream>>>(Qh, Kh, Vth, mlen, qlen, ctx,
                                                align);
}

// Round 3
// 418.044 us; speedup vs baseline: 1.0713x; 1.0713x over previous
//
#include <hip/hip_runtime.h>

#define NB 8
#define NTQ 1024
#define NTM 1024
#define ND 512
#define NATTN 512
#define NH 8
#define NDH 64

typedef _Float16 half8 __attribute__((ext_vector_type(8)));
typedef float f32x4 __attribute__((ext_vector_type(4)));

// ---------------------------------------------------------------------------
// Projection: out = A @ W for A in {inputs, memory, memory}, W in {Wq,Wk,Wv}.
// z=0 -> Q fp16 [b][h][t][64]; z=1 -> K fp16 [b][h][m][64];
// z=2 -> V transposed fp16 [b][h][64][m]  (so attn PV B-frags are contiguous)
// (round-0 structure, known-good)
// ---------------------------------------------------------------------------
__global__ __launch_bounds__(256) void proj_kernel(
    const float* __restrict__ inputs, const float* __restrict__ memory,
    const float* __restrict__ Wq, const float* __restrict__ Wk,
    const float* __restrict__ Wv,
    _Float16* __restrict__ Qh, _Float16* __restrict__ Kh,
    _Float16* __restrict__ Vth) {
  const int z = blockIdx.z;
  const float* __restrict__ A = (z == 0) ? inputs : memory;
  const float* __restrict__ W = (z == 0) ? Wq : ((z == 1) ? Wk : Wv);
  const int row0 = blockIdx.y * 64;  // 0..8191 (b*1024 + t)
  const int col0 = blockIdx.x * 64;  // 0..511  (h*64 + d)

  __shared__ __align__(16) _Float16 As[64][72];
  __shared__ __align__(16) _Float16 Wt[64][72];  // Wt[c][k]

  const int t = threadIdx.x;
  const int w = t >> 6;
  const int L = t & 63;
  const int lrow = L & 15;
  const int quad = L >> 4;
  const int sr = t >> 2;        // 0..63
  const int sc = (t & 3) * 16;  // 0,16,32,48

  const f32x4 zf = {0.f, 0.f, 0.f, 0.f};
  f32x4 acc[4];
#pragma unroll
  for (int i = 0; i < 4; i++) acc[i] = zf;

  for (int k0 = 0; k0 < ND; k0 += 64) {
    // stage A tile fp32->fp16
    {
      const float4* src = (const float4*)(A + (size_t)(row0 + sr) * ND + k0 + sc);
      float4 f0 = src[0], f1 = src[1], f2 = src[2], f3 = src[3];
      half8 h0, h1;
      h0[0] = (_Float16)f0.x; h0[1] = (_Float16)f0.y; h0[2] = (_Float16)f0.z; h0[3] = (_Float16)f0.w;
      h0[4] = (_Float16)f1.x; h0[5] = (_Float16)f1.y; h0[6] = (_Float16)f1.z; h0[7] = (_Float16)f1.w;
      h1[0] = (_Float16)f2.x; h1[1] = (_Float16)f2.y; h1[2] = (_Float16)f2.z; h1[3] = (_Float16)f2.w;
      h1[4] = (_Float16)f3.x; h1[5] = (_Float16)f3.y; h1[6] = (_Float16)f3.z; h1[7] = (_Float16)f3.w;
      *(half8*)&As[sr][sc] = h0;
      *(half8*)&As[sr][sc + 8] = h1;
    }
    // stage W tile transposed: Wt[c][k]
    {
      const float4* src = (const float4*)(W + (size_t)(k0 + sr) * NATTN + col0 + sc);
      float4 g0 = src[0], g1 = src[1], g2 = src[2], g3 = src[3];
      float gv[16];
      *(float4*)&gv[0] = g0; *(float4*)&gv[4] = g1;
      *(float4*)&gv[8] = g2; *(float4*)&gv[12] = g3;
#pragma unroll
      for (int j = 0; j < 16; j++) Wt[sc + j][sr] = (_Float16)gv[j];
    }
    __syncthreads();
#pragma unroll
    for (int ks = 0; ks < 2; ks++) {
      half8 a = *(const half8*)&As[w * 16 + lrow][ks * 32 + quad * 8];
#pragma unroll
      for (int nt = 0; nt < 4; nt++) {
        half8 b = *(const half8*)&Wt[nt * 16 + lrow][ks * 32 + quad * 8];
        acc[nt] = __builtin_amdgcn_mfma_f32_16x16x32_f16(a, b, acc[nt], 0, 0, 0);
      }
    }
    __syncthreads();
  }

  const int b = row0 >> 10;
  const int tr0 = row0 & 1023;
  const int hh = col0 >> 6;
  if (z <= 1) {
    _Float16* dst = (z == 0 ? Qh : Kh) + (size_t)(b * NH + hh) * NTQ * NDH;
#pragma unroll
    for (int nt = 0; nt < 4; nt++) {
#pragma unroll
      for (int r = 0; r < 4; r++) {
        int trow = tr0 + w * 16 + quad * 4 + r;
        int d = nt * 16 + lrow;
        dst[(size_t)trow * NDH + d] = (_Float16)acc[nt][r];
      }
    }
  } else {
    // rebounce through LDS to write V transposed coalesced: As reused as [d][t]
#pragma unroll
    for (int nt = 0; nt < 4; nt++) {
#pragma unroll
      for (int r = 0; r < 4; r++)
        As[nt * 16 + lrow][w * 16 + quad * 4 + r] = (_Float16)acc[nt][r];
    }
    __syncthreads();
    _Float16* dst = Vth + ((size_t)(b * NH + hh) * NDH + sr) * NTM + tr0 + sc;
    *(half8*)dst = *(const half8*)&As[sr][sc];
    *(half8*)(dst + 8) = *(const half8*)&As[sr][sc + 8];
  }
}

// ---------------------------------------------------------------------------
// Attention (round-0 structure + causal/length tile skipping).
// grid = (bh=64, qt=16): same bh adjacent -> K/V L2 locality.
// q-tile qt only computes m-tiles mt < n_comp; n_comp = 16 for blocks
// containing q>=qlen rows (uniform rows need full V sum), else
// min(qt+1, ceil(mlen/64)). Skipped tiles contribute exactly 0 to rowsum,
// alignments (zero-filled), and P@V — bitwise identical to computing them.
// ---------------------------------------------------------------------------
__global__ __launch_bounds__(256) void attn_kernel(
    const _Float16* __restrict__ Qh, const _Float16* __restrict__ Kh,
    const _Float16* __restrict__ Vth, const int* __restrict__ mem_len,
    const int* __restrict__ qry_len, float* __restrict__ ctx_out,
    float* __restrict__ align_out) {
  const int bh = blockIdx.x;  // 0..63
  const int qt = blockIdx.y;  // 0..15
  const int bb = bh >> 3;
  const int hh = bh & 7;
  const int q0 = qt * 64;

  __shared__ __align__(16) _Float16 Qs[64][72];
  __shared__ __align__(16) _Float16 Ks[64][72];
  __shared__ __align__(16) _Float16 Vts[64][72];   // [d][m_local]
  __shared__ __align__(16) _Float16 Ps[4][16][72]; // per-wave P (A-layout src)

  const int t = threadIdx.x, w = t >> 6, L = t & 63;
  const int lrow = L & 15, quad = L >> 4;
  const int qlen = qry_len[bb], mlen = mem_len[bb];
  const int mtop = (mlen + 63) >> 6;
  const int n_comp = (q0 + 63 >= qlen) ? 16 : min(qt + 1, mtop);
  const _Float16* Qbase = Qh + (size_t)bh * NTQ * NDH;
  const _Float16* Kbase = Kh + (size_t)bh * NTM * NDH;
  const _Float16* Vbase = Vth + (size_t)bh * NDH * NTM;
  const int sr = t >> 2, sc = (t & 3) * 16;
  const f32x4 zf = {0.f, 0.f, 0.f, 0.f};
  float* abase = align_out + (size_t)bh * NTQ * NTM;

  // ---- zero-fill skipped alignment columns (ref has exact 0 there) ----
  if (n_comp < 16) {
    const int c0 = n_comp * 64;
    float* rp = abase + (size_t)(q0 + sr) * NTM;
    const float4 z4 = {0.f, 0.f, 0.f, 0.f};
    for (int c = c0 + (t & 3) * 4; c < NTM; c += 16) *(float4*)(rp + c) = z4;
  }

  {
    const half8* src = (const half8*)(Qbase + (size_t)(q0 + sr) * NDH + sc);
    *(half8*)&Qs[sr][sc] = src[0];
    *(half8*)&Qs[sr][sc + 8] = src[1];
  }
  const int qg = q0 + w * 16 + quad * 4;  // + r = global q row
  float rowsum[4] = {0.f, 0.f, 0.f, 0.f};
  __syncthreads();

  // ---- pass 1: denominators ----
  for (int mt = 0; mt < n_comp; mt++) {
    {
      const half8* src = (const half8*)(Kbase + (size_t)(mt * 64 + sr) * NDH + sc);
      *(half8*)&Ks[sr][sc] = src[0];
      *(half8*)&Ks[sr][sc + 8] = src[1];
    }
    __syncthreads();
    f32x4 sacc[4];
#pragma unroll
    for (int i = 0; i < 4; i++) sacc[i] = zf;
#pragma unroll
    for (int ks = 0; ks < 2; ks++) {
      half8 a = *(const half8*)&Qs[w * 16 + lrow][ks * 32 + quad * 8];
#pragma unroll
      for (int nt = 0; nt < 4; nt++) {
        half8 b = *(const half8*)&Ks[nt * 16 + lrow][ks * 32 + quad * 8];
        sacc[nt] = __builtin_amdgcn_mfma_f32_16x16x32_f16(a, b, sacc[nt], 0, 0, 0);
      }
    }
#pragma unroll
    for (int nt = 0; nt < 4; nt++) {
      int m = mt * 64 + nt * 16 + lrow;
#pragma unroll
      for (int r = 0; r < 4; r++) {
        int q = qg + r;
        float p;
        if (q >= qlen) p = 1.0f;               // uniform row
        else if (m > q || m >= mlen) p = 0.0f; // masked
        else p = __expf(sacc[nt][r] * 0.125f);
        rowsum[r] += p;
      }
    }
    __syncthreads();
  }
  float inv[4];
#pragma unroll
  for (int r = 0; r < 4; r++) {
    float s = rowsum[r];
    s += __shfl_xor(s, 1, 16);
    s += __shfl_xor(s, 2, 16);
    s += __shfl_xor(s, 4, 16);
    s += __shfl_xor(s, 8, 16);
    inv[r] = 1.0f / s;
  }

  // ---- pass 2: alignments + contexts ----
  f32x4 cacc[4];
#pragma unroll
  for (int i = 0; i < 4; i++) cacc[i] = zf;

  for (int mt = 0; mt < n_comp; mt++) {
    {
      const half8* src = (const half8*)(Kbase + (size_t)(mt * 64 + sr) * NDH + sc);
      *(half8*)&Ks[sr][sc] = src[0];
      *(half8*)&Ks[sr][sc + 8] = src[1];
      const half8* vsrc = (const half8*)(Vbase + (size_t)sr * NTM + mt * 64 + sc);
      *(half8*)&Vts[sr][sc] = vsrc[0];
      *(half8*)&Vts[sr][sc + 8] = vsrc[1];
    }
    __syncthreads();
    f32x4 sacc[4];
#pragma unroll
    for (int i = 0; i < 4; i++) sacc[i] = zf;
#pragma unroll
    for (int ks = 0; ks < 2; ks++) {
      half8 a = *(const half8*)&Qs[w * 16 + lrow][ks * 32 + quad * 8];
#pragma unroll
      for (int nt = 0; nt < 4; nt++) {
        half8 b = *(const half8*)&Ks[nt * 16 + lrow][ks * 32 + quad * 8];
        sacc[nt] = __builtin_amdgcn_mfma_f32_16x16x32_f16(a, b, sacc[nt], 0, 0, 0);
      }
    }
#pragma unroll
    for (int nt = 0; nt < 4; nt++) {
      int m = mt * 64 + nt * 16 + lrow;
#pragma unroll
      for (int r = 0; r < 4; r++) {
        int q = qg + r;
        float p;
        if (q >= qlen) p = inv[r];
        else if (m > q || m >= mlen) p = 0.0f;
        else p = __expf(sacc[nt][r] * 0.125f) * inv[r];
        abase[(size_t)q * NTM + m] = p;
        Ps[w][quad * 4 + r][nt * 16 + lrow] = (_Float16)p;
      }
    }
    // P @ V  (Ps is per-wave; in-wave DS ordering suffices, no barrier —
    // validated structure from round-0)
#pragma unroll
    for (int ks = 0; ks < 2; ks++) {
      half8 a = *(const half8*)&Ps[w][lrow][ks * 32 + quad * 8];
#pragma unroll
      for (int dt = 0; dt < 4; dt++) {
        half8 b = *(const half8*)&Vts[dt * 16 + lrow][ks * 32 + quad * 8];
        cacc[dt] = __builtin_amdgcn_mfma_f32_16x16x32_f16(a, b, cacc[dt], 0, 0, 0);
      }
    }
    __syncthreads();
  }

  float* cbase = ctx_out + (size_t)bb * NTQ * NATTN + (size_t)hh * NDH;
#pragma unroll
  for (int dt = 0; dt < 4; dt++) {
#pragma unroll
    for (int r = 0; r < 4; r++) {
      int q = qg + r;
      cbase[(size_t)q * NATTN + dt * 16 + lrow] = cacc[dt][r];
    }
  }
}

extern "C" void kernel_launch(void* const* d_in, const int* in_sizes, int n_in,
                              void* d_out, int out_size, void* d_ws,
                              size_t ws_size, hipStream_t stream) {
  const float* inputs = (const float*)d_in[0];
  const float* memory = (const float*)d_in[1];
  const float* Wq = (const float*)d_in[2];
  const float* Wk = (const float*)d_in[3];
  const float* Wv = (const float*)d_in[4];
  const int* mlen = (const int*)d_in[5];
  const int* qlen = (const int*)d_in[6];

  float* ctx = (float*)d_out;                     // (B,TQ,ATTN)
  float* align = ctx + (size_t)NB * NTQ * NATTN;  // (B,H,TQ,TM)

  _Float16* Qh = (_Float16*)d_ws;                   // 8 MB
  _Float16* Kh = Qh + (size_t)NB * NH * NTQ * NDH;  // 8 MB
  _Float16* Vth = Kh + (size_t)NB * NH * NTM * NDH; // 8 MB

  proj_kernel<<<dim3(8, 128, 3), 256, 0, stream>>>(inputs, memory, Wq, Wk, Wv,
                                                   Qh, Kh, Vth);
  attn_kernel<<<dim3(64, 16), 256, 0, stream>>>(Qh, Kh, Vth, mlen, qlen, ctx,
                                                align);
}